// Round 12
// baseline (5956.934 us; speedup 1.0000x reference)
//
#include <hip/hip_runtime.h>
#include <cstdint>

#define Hn 36
#define G4 144          // 4*H gate rows
#define TT 512
#define BB 2048

__device__ __forceinline__ float sigf(float x) { return 1.0f / (1.0f + __expf(-x)); }
__device__ __forceinline__ float tanh_fast(float x) {
    float e = __expf(2.0f * x);          // exact +-1 limits via over/underflow
    return 1.0f - 2.0f / (e + 1.0f);
}

// ---- K1 named-register weight quads (K1 measured ~420us; untouched) ----
#define REP9(M, P)  M(P,0) M(P,1) M(P,2) M(P,3) M(P,4) M(P,5) M(P,6) M(P,7) M(P,8)
#define DECLQ(P, i) float P##i##x, P##i##y, P##i##z, P##i##w;
#define LOADQ(P, i) { float4 _t = wp[i]; P##i##x = _t.x; P##i##y = _t.y; P##i##z = _t.z; P##i##w = _t.w; }
#define PINQ(P, i)  asm volatile("" : "+v"(P##i##x), "+v"(P##i##y), "+v"(P##i##z), "+v"(P##i##w));
#define FMAQ(P, i)                                                        \
    {  float4 hv = *(const float4*)&hb[(i) * 4];                          \
       z0 = fmaf(P##i##x, hv.x, z0); z1 = fmaf(P##i##y, hv.y, z1);        \
       z2 = fmaf(P##i##z, hv.z, z2); z3 = fmaf(P##i##w, hv.w, z3); }

// array-based dots (fallback kernel only)
#define DOT36(W, H, Z0, Z1, Z2, Z3)                        \
    do {                                                   \
        _Pragma("unroll") for (int _k = 0; _k < 9; ++_k) { \
            float4 hv = *(const float4*)&(H)[_k * 4];      \
            Z0 = fmaf((W)[_k * 4 + 0], hv.x, Z0);          \
            Z1 = fmaf((W)[_k * 4 + 1], hv.y, Z1);          \
            Z2 = fmaf((W)[_k * 4 + 2], hv.z, Z2);          \
            Z3 = fmaf((W)[_k * 4 + 3], hv.w, Z3);          \
        }                                                  \
    } while (0)

#define DOT72(W, H, Z0, Z1, Z2, Z3)                         \
    do {                                                    \
        _Pragma("unroll") for (int _k = 0; _k < 18; ++_k) { \
            float4 hv = *(const float4*)&(H)[_k * 4];       \
            Z0 = fmaf((W)[_k * 4 + 0], hv.x, Z0);           \
            Z1 = fmaf((W)[_k * 4 + 1], hv.y, Z1);           \
            Z2 = fmaf((W)[_k * 4 + 2], hv.z, Z2);           \
            Z3 = fmaf((W)[_k * 4 + 3], hv.w, Z3);           \
        }                                                   \
    } while (0)

// ============ K1: layer-0 REVERSE scan, full batch -> h0r (151 MB ws) ========
#define SG1 4
#define NTK1 (SG1 * G4)   // 576
__global__ __launch_bounds__(NTK1) void l0rev_kernel(
    const float* __restrict__ x,
    const float* __restrict__ Wih, const float* __restrict__ Whh,
    const float* __restrict__ bih, const float* __restrict__ bhh,
    float* __restrict__ h0r)
{
    const int tid = threadIdx.x;
    const int cc  = tid / G4;
    const int g   = tid % G4;
    const int b   = blockIdx.x * SG1 + cc;

    __shared__ float xs[SG1][TT];
    __shared__ float hs[SG1][40];
    __shared__ float zs[SG1][G4];

    for (int i = g; i < TT; i += G4) xs[cc][i] = x[(size_t)b * TT + i];

    REP9(DECLQ, R)
    {
        const float4* wp = (const float4*)(Whh + g * Hn);
        REP9(LOADQ, R)
    }
    float wx   = Wih[g];
    float bias = bih[g] + bhh[g];
    REP9(PINQ, R)
    asm volatile("" : "+v"(wx), "+v"(bias));

    if (g < 40) hs[cc][g] = 0.0f;
    float c = 0.0f;
    __syncthreads();

    float* dst = h0r + (size_t)b * TT * Hn;

    for (int s = 0; s < TT; ++s) {
        const int t = TT - 1 - s;
        float z0 = fmaf(xs[cc][t], wx, bias), z1 = 0.f, z2 = 0.f, z3 = 0.f;
        {
            const float* hb = hs[cc];
            REP9(FMAQ, R)
        }
        zs[cc][g] = (z0 + z1) + (z2 + z3);
        __syncthreads();
        if (g < Hn) {
            float zi = zs[cc][g], zf = zs[cc][g + 36], zg = zs[cc][g + 72], zo = zs[cc][g + 108];
            c = sigf(zf) * c + sigf(zi) * tanh_fast(zg);
            float h = sigf(zo) * tanh_fast(c);
            hs[cc][g] = h;
            dst[(size_t)t * Hn + g] = h;
        }
        __syncthreads();
    }
}

// ======= K2: chain-per-lane fused L0f + L1f (skewed) + 1-step L1r + FC =======
// 16 chains/block, lane = (c = lane&15, s = lane>>4). Each lane computes whole
// dots for rows r = batch*4 + s. Weight reads: 4-addr x 16-bcast ds_read_b128.
#define CH2  16
#define NT2  512          // 8 waves
#define NB2  (BB / CH2)   // 128 blocks
#define H0ST 44           // extended L0 vec/row stride: [h0f(36)|x|1|pad] (44%32=12)
#define H1ST 116          // extended L1 vec/row stride: [h0f|h0r|h1|1|pad] (116%32=20)

__global__ __launch_bounds__(NT2) void fused2_kernel(
    const float* __restrict__ x,
    const float* __restrict__ Wih0f, const float* __restrict__ Whh0f,
    const float* __restrict__ bih0f, const float* __restrict__ bhh0f,
    const float* __restrict__ Wih1f, const float* __restrict__ Whh1f,
    const float* __restrict__ bih1f, const float* __restrict__ bhh1f,
    const float* __restrict__ Wih1r,
    const float* __restrict__ bih1r, const float* __restrict__ bhh1r,
    const float* __restrict__ fcW, const float* __restrict__ fcb,
    const float* __restrict__ h0r,
    float* __restrict__ out)
{
    const int tid  = threadIdx.x;
    const int wv   = tid >> 6;
    const int lane = tid & 63;
    const int c    = lane & 15;
    const int s    = lane >> 4;
    const int base = blockIdx.x * CH2;

    __shared__ float W0e[G4 * H0ST];     // 25.3 KB  [Whh0f | Wih0f | bias | 0]
    __shared__ float W1e[G4 * H1ST];     // 66.8 KB  [Wih1f(72) | Whh1f(36) | bias | 0]
    __shared__ float h0e[CH2 * H0ST];    // 2.8 KB   [h0f(t) | x(t+1) | 1 | 0]
    __shared__ float hcat[CH2 * H1ST];   // 7.4 KB   [h0f(t) | h0r(t) | h1(t-1) | 1 | 0]
    __shared__ float xs[CH2][520];       // 33.3 KB  (zero-padded past TT)
    __shared__ float zb0[G4][CH2];       // 9.2 KB
    __shared__ float zb1[G4][CH2];       // 9.2 KB
    __shared__ float red[CH2][4];

    // ---------------- init staging ----------------
    for (int i = tid; i < CH2 * 520; i += NT2) {
        int cc = i / 520, t = i % 520;
        xs[cc][t] = (t < TT) ? x[(size_t)(base + cc) * TT + t] : 0.0f;
    }
    for (int i = tid; i < G4 * H0ST; i += NT2) {
        int r = i / H0ST, k = i % H0ST;
        float v = 0.0f;
        if (k < 36)      v = Whh0f[r * 36 + k];
        else if (k == 36) v = Wih0f[r];
        else if (k == 37) v = bih0f[r] + bhh0f[r];
        W0e[i] = v;
    }
    for (int i = tid; i < G4 * H1ST; i += NT2) {
        int r = i / H1ST, k = i % H1ST;
        float v = 0.0f;
        if (k < 72)       v = Wih1f[r * 72 + k];
        else if (k < 108) v = Whh1f[r * 36 + (k - 72)];
        else if (k == 108) v = bih1f[r] + bhh1f[r];
        W1e[i] = v;
    }
    for (int i = tid; i < CH2 * H0ST; i += NT2) {
        int cc = i / H0ST, k = i % H0ST;
        h0e[i] = (k == 36) ? x[(size_t)(base + cc) * TT] : (k == 37 ? 1.0f : 0.0f);
    }
    for (int i = tid; i < CH2 * H1ST; i += NT2) {
        int cc = i / H1ST, k = i % H1ST;
        float v = 0.0f;
        if (k >= 36 && k < 72) v = h0r[(size_t)(base + cc) * TT * Hn + (k - 36)]; // h0r(0)
        else if (k == 108)     v = 1.0f;
        hcat[i] = v;
    }
    float c0reg[9], c1reg[9];
#pragma unroll
    for (int j = 0; j < 9; ++j) { c0reg[j] = 0.f; c1reg[j] = 0.f; }
    __syncthreads();

    // ---------------- prologue: h0f(0) ----------------
    if (wv < 2) {
        const int b0 = wv * 18;
        for (int b = 0; b < 18; ++b) {
            const int r = (b0 + b) * 4 + s;
            const float4* wr = (const float4*)&W0e[r * H0ST];
            const float4* hv = (const float4*)&h0e[c * H0ST];
            float z = 0.f;
#pragma unroll
            for (int q = 0; q < 10; ++q) {
                float4 w = wr[q], h = hv[q];
                z = fmaf(w.x, h.x, z); z = fmaf(w.y, h.y, z);
                z = fmaf(w.z, h.z, z); z = fmaf(w.w, h.w, z);
            }
            zb0[r][c] = z;
        }
    }
    __syncthreads();
    if (wv == 0) {
#pragma unroll
        for (int j = 0; j < 9; ++j) {
            const int u = s * 9 + j;
            float zi = zb0[u][c], zf = zb0[36 + u][c], zg = zb0[72 + u][c], zo = zb0[108 + u][c];
            c0reg[j] = sigf(zf) * c0reg[j] + sigf(zi) * tanh_fast(zg);
            float h = sigf(zo) * tanh_fast(c0reg[j]);
            h0e[c * H0ST + u] = h;
            hcat[c * H1ST + u] = h;
        }
        if (s == 0) h0e[c * H0ST + 36] = xs[c][1];
    }
    __syncthreads();

    // wv7 h0r prefetch mapping: 64 lanes x 9 floats = 16 chains x 36
    const int li = lane * 9;
    const int pc = li / 36;
    const int pk = li % 36;
    float rv[9];

    // ---------------- main loop ----------------
    for (int t = 0; t < TT; ++t) {
        if (wv == 7 && t + 1 < TT) {
            const float* src = h0r + (size_t)(base + pc) * TT * Hn + (size_t)(t + 1) * Hn + pk;
#pragma unroll
            for (int q = 0; q < 9; ++q) rv[q] = src[q];
        }
        if (wv < 2) {
            const int b0 = wv * 18;
            for (int b = 0; b < 18; ++b) {
                const int r = (b0 + b) * 4 + s;
                const float4* wr = (const float4*)&W0e[r * H0ST];
                const float4* hv = (const float4*)&h0e[c * H0ST];
                float z = 0.f;
#pragma unroll
                for (int q = 0; q < 10; ++q) {
                    float4 w = wr[q], h = hv[q];
                    z = fmaf(w.x, h.x, z); z = fmaf(w.y, h.y, z);
                    z = fmaf(w.z, h.z, z); z = fmaf(w.w, h.w, z);
                }
                zb0[r][c] = z;
            }
        } else {
            const int b0 = (wv - 2) * 6;
            for (int b = 0; b < 6; ++b) {
                const int r = (b0 + b) * 4 + s;
                const float4* wr = (const float4*)&W1e[r * H1ST];
                const float4* hv = (const float4*)&hcat[c * H1ST];
                float z = 0.f;
#pragma unroll
                for (int q = 0; q < 28; ++q) {
                    float4 w = wr[q], h = hv[q];
                    z = fmaf(w.x, h.x, z); z = fmaf(w.y, h.y, z);
                    z = fmaf(w.z, h.z, z); z = fmaf(w.w, h.w, z);
                }
                zb1[r][c] = z;
            }
        }
        __syncthreads();

        if (wv == 0) {                         // L0 combine -> h0f(t+1)
#pragma unroll
            for (int j = 0; j < 9; ++j) {
                const int u = s * 9 + j;
                float zi = zb0[u][c], zf = zb0[36 + u][c], zg = zb0[72 + u][c], zo = zb0[108 + u][c];
                c0reg[j] = sigf(zf) * c0reg[j] + sigf(zi) * tanh_fast(zg);
                float h = sigf(zo) * tanh_fast(c0reg[j]);
                h0e[c * H0ST + u] = h;
                if (t + 1 < TT) hcat[c * H1ST + u] = h;   // keep h0f(511) for tail
            }
            if (s == 0) h0e[c * H0ST + 36] = xs[c][t + 2];
        } else if (wv == 2) {                  // L1 combine -> h1(t)
#pragma unroll
            for (int j = 0; j < 9; ++j) {
                const int u = s * 9 + j;
                float zi = zb1[u][c], zf = zb1[36 + u][c], zg = zb1[72 + u][c], zo = zb1[108 + u][c];
                c1reg[j] = sigf(zf) * c1reg[j] + sigf(zi) * tanh_fast(zg);
                hcat[c * H1ST + 72 + u] = sigf(zo) * tanh_fast(c1reg[j]);
            }
        } else if (wv == 7 && t + 1 < TT) {    // stage h0r(t+1)
#pragma unroll
            for (int q = 0; q < 9; ++q)
                hcat[pc * H1ST + 36 + pk + q] = rv[q];
        }
        __syncthreads();
    }

    // ---------------- tail: 1-step L1 reverse (h0=c0=0) + FC ----------------
    for (int b = wv; b < 36; b += 8) {
        const int r = b * 4 + s;
        const float4* wr = (const float4*)(Wih1r + r * 72);
        const float4* hv = (const float4*)&hcat[c * H1ST];   // [h0f(511)|h0r(511)]
        float z = bih1r[r] + bhh1r[r];
#pragma unroll
        for (int q = 0; q < 18; ++q) {
            float4 w = wr[q], h = hv[q];
            z = fmaf(w.x, h.x, z); z = fmaf(w.y, h.y, z);
            z = fmaf(w.z, h.z, z); z = fmaf(w.w, h.w, z);
        }
        zb1[r][c] = z;
    }
    __syncthreads();
    if (wv == 0) {
        float acc = 0.f;
#pragma unroll
        for (int j = 0; j < 9; ++j) {
            const int u = s * 9 + j;
            float zi = zb1[u][c], zg = zb1[72 + u][c], zo = zb1[108 + u][c];
            float cR = sigf(zi) * tanh_fast(zg);   // c0=0: forget term vanishes
            float hR = sigf(zo) * tanh_fast(cR);
            acc = fmaf(fcW[36 + u], hR, acc);
            acc = fmaf(fcW[u], hcat[c * H1ST + 72 + u], acc);
        }
        red[c][s] = acc;
    }
    __syncthreads();
    if (tid < CH2)
        out[base + tid] = fcb[0] + red[tid][0] + red[tid][1] + red[tid][2] + red[tid][3];
}

// ================= FALLBACK PATH (zero workspace, ckpt/recompute) ============
__global__ __launch_bounds__(G4, 1) void fused_all_kernel(
    const float* __restrict__ x,
    const float* __restrict__ Wih0f, const float* __restrict__ Whh0f,
    const float* __restrict__ bih0f, const float* __restrict__ bhh0f,
    const float* __restrict__ Wih0r, const float* __restrict__ Whh0r,
    const float* __restrict__ bih0r, const float* __restrict__ bhh0r,
    const float* __restrict__ Wih1f, const float* __restrict__ Whh1f,
    const float* __restrict__ bih1f, const float* __restrict__ bhh1f,
    const float* __restrict__ Wih1r,
    const float* __restrict__ bih1r, const float* __restrict__ bhh1r,
    const float* __restrict__ fcW, const float* __restrict__ fcb,
    float* __restrict__ out)
{
    const int g = threadIdx.x;
    const int b = blockIdx.x;

    __shared__ float xs[TT];
    __shared__ float cbuf[64][Hn];
    __shared__ float ckpt_h[8][Hn], ckpt_c[8][Hn];
    __shared__ float hr[40], h0s[80], hs1[40], zs[G4], red[40];

    for (int i = g; i < TT; i += G4) xs[i] = x[(size_t)b * TT + i];

    float wr[Hn], wf[Hn];
#pragma unroll
    for (int k = 0; k < Hn; ++k) wr[k] = Whh0r[g * Hn + k];
#pragma unroll
    for (int k = 0; k < Hn; ++k) wf[k] = Whh0f[g * Hn + k];
    const float wxr = Wih0r[g], br = bih0r[g] + bhh0r[g];
    const float wxf = Wih0f[g], bf = bih0f[g] + bhh0f[g];
    float w1i[72];
#pragma unroll
    for (int k = 0; k < 72; ++k) w1i[k] = Wih1f[g * 72 + k];
    float w1h[Hn];
#pragma unroll
    for (int k = 0; k < Hn; ++k) w1h[k] = Whh1f[g * Hn + k];
    const float b1 = bih1f[g] + bhh1f[g];

    if (g < Hn) hr[g] = 0.0f;
    float cr = 0.0f;
    __syncthreads();
    for (int s = 0; s < TT; ++s) {
        const int t = TT - 1 - s;
        if ((t & 63) == 63 && g < Hn) { ckpt_h[t >> 6][g] = hr[g]; ckpt_c[t >> 6][g] = cr; }
        float z0 = fmaf(xs[t], wxr, br), z1 = 0.f, z2 = 0.f, z3 = 0.f;
        DOT36(wr, hr, z0, z1, z2, z3);
        zs[g] = (z0 + z1) + (z2 + z3);
        __syncthreads();
        if (g < Hn) {
            float zi = zs[g], zf = zs[g + 36], zg = zs[g + 72], zo = zs[g + 108];
            cr = sigf(zf) * cr + sigf(zi) * tanh_fast(zg);
            hr[g] = sigf(zo) * tanh_fast(cr);
        }
        __syncthreads();
    }

    if (g < Hn) { h0s[g] = 0.0f; hs1[g] = 0.0f; }
    float c0 = 0.0f, c1 = 0.0f;
    __syncthreads();

    for (int m = 0; m < 8; ++m) {
        if (g < Hn) { hr[g] = ckpt_h[m][g]; cr = ckpt_c[m][g]; }
        __syncthreads();
        for (int j = 0; j < 64; ++j) {
            const int t = m * 64 + 63 - j;
            float z0 = fmaf(xs[t], wxr, br), z1 = 0.f, z2 = 0.f, z3 = 0.f;
            DOT36(wr, hr, z0, z1, z2, z3);
            zs[g] = (z0 + z1) + (z2 + z3);
            __syncthreads();
            if (g < Hn) {
                float zi = zs[g], zf = zs[g + 36], zg = zs[g + 72], zo = zs[g + 108];
                cr = sigf(zf) * cr + sigf(zi) * tanh_fast(zg);
                float h = sigf(zo) * tanh_fast(cr);
                hr[g] = h;
                cbuf[t & 63][g] = h;
            }
            __syncthreads();
        }
        for (int j = 0; j < 64; ++j) {
            const int t = m * 64 + j;
            float z0 = fmaf(xs[t], wxf, bf), z1 = 0.f, z2 = 0.f, z3 = 0.f;
            DOT36(wf, h0s, z0, z1, z2, z3);
            zs[g] = (z0 + z1) + (z2 + z3);
            __syncthreads();
            if (g < Hn) {
                float zi = zs[g], zf = zs[g + 36], zg = zs[g + 72], zo = zs[g + 108];
                c0 = sigf(zf) * c0 + sigf(zi) * tanh_fast(zg);
                h0s[g] = sigf(zo) * tanh_fast(c0);
            } else if (g < 72) {
                h0s[g] = cbuf[j][g - 36];
            }
            __syncthreads();
            float y0 = b1, y1 = 0.f, y2 = 0.f, y3 = 0.f;
            DOT72(w1i, h0s, y0, y1, y2, y3);
            DOT36(w1h, hs1, y0, y1, y2, y3);
            zs[g] = (y0 + y1) + (y2 + y3);
            __syncthreads();
            if (g < Hn) {
                float zi = zs[g], zf = zs[g + 36], zg = zs[g + 72], zo = zs[g + 108];
                c1 = sigf(zf) * c1 + sigf(zi) * tanh_fast(zg);
                hs1[g] = sigf(zo) * tanh_fast(c1);
            }
            __syncthreads();
        }
    }

    float zR = bih1r[g] + bhh1r[g];
#pragma unroll
    for (int k = 0; k < 72; ++k) zR = fmaf(Wih1r[g * 72 + k], h0s[k], zR);
    zs[g] = zR;
    __syncthreads();
    if (g < Hn) {
        float zi = zs[g], zg = zs[g + 72], zo = zs[g + 108];
        float c  = sigf(zi) * tanh_fast(zg);
        float hrv = sigf(zo) * tanh_fast(c);
        red[g] = fcW[36 + g] * hrv + fcW[g] * hs1[g];
    }
    __syncthreads();
    if (g == 0) {
        float s = fcb[0];
        for (int j = 0; j < Hn; ++j) s += red[j];
        out[b] = s;
    }
}

extern "C" void kernel_launch(void* const* d_in, const int* in_sizes, int n_in,
                              void* d_out, int out_size, void* d_ws, size_t ws_size,
                              hipStream_t stream)
{
    const float* x     = (const float*)d_in[0];
    const float* Wih0f = (const float*)d_in[1];
    const float* Whh0f = (const float*)d_in[2];
    const float* bih0f = (const float*)d_in[3];
    const float* bhh0f = (const float*)d_in[4];
    const float* Wih0r = (const float*)d_in[5];
    const float* Whh0r = (const float*)d_in[6];
    const float* bih0r = (const float*)d_in[7];
    const float* bhh0r = (const float*)d_in[8];
    const float* Wih1f = (const float*)d_in[9];
    const float* Whh1f = (const float*)d_in[10];
    const float* bih1f = (const float*)d_in[11];
    const float* bhh1f = (const float*)d_in[12];
    const float* Wih1r = (const float*)d_in[13];
    const float* bih1r = (const float*)d_in[15];
    const float* bhh1r = (const float*)d_in[16];
    const float* fcW   = (const float*)d_in[17];
    const float* fcb   = (const float*)d_in[18];

    const size_t need = (size_t)BB * TT * Hn * sizeof(float);   // 151 MB (known-safe)
    if (d_ws != nullptr && ws_size >= need) {
        float* h0r = (float*)d_ws;
        l0rev_kernel<<<BB / SG1, NTK1, 0, stream>>>(x, Wih0r, Whh0r, bih0r, bhh0r, h0r);
        fused2_kernel<<<NB2, NT2, 0, stream>>>(
            x, Wih0f, Whh0f, bih0f, bhh0f, Wih1f, Whh1f, bih1f, bhh1f,
            Wih1r, bih1r, bhh1r, fcW, fcb, h0r, (float*)d_out);
    } else {
        fused_all_kernel<<<BB, G4, 0, stream>>>(
            x, Wih0f, Whh0f, bih0f, bhh0f, Wih0r, Whh0r, bih0r, bhh0r,
            Wih1f, Whh1f, bih1f, bhh1f, Wih1r, bih1r, bhh1r, fcW, fcb,
            (float*)d_out);
    }
}

// Round 13
// 2036.176 us; speedup vs baseline: 2.9255x; 2.9255x over previous
//
#include <hip/hip_runtime.h>
#include <cstdint>

#define Hn 36
#define G4 144          // 4*H gate rows
#define TT 512
#define BB 2048

__device__ __forceinline__ float sigf(float x) { return 1.0f / (1.0f + __expf(-x)); }
__device__ __forceinline__ float tanh_fast(float x) {
    float e = __expf(2.0f * x);          // exact +-1 limits via over/underflow
    return 1.0f - 2.0f / (e + 1.0f);
}

// ---- named-register weight quads ----
#define REP9(M, P)  M(P,0) M(P,1) M(P,2) M(P,3) M(P,4) M(P,5) M(P,6) M(P,7) M(P,8)
#define DECLQ(P, i) float P##i##x, P##i##y, P##i##z, P##i##w;
#define LOADQ(P, i) { float4 _t = wp[i]; P##i##x = _t.x; P##i##y = _t.y; P##i##z = _t.z; P##i##w = _t.w; }
#define PINQ(P, i)  asm volatile("" : "+v"(P##i##x), "+v"(P##i##y), "+v"(P##i##z), "+v"(P##i##w));
#define FMAQ(P, i)                                                        \
    {  float4 hv = *(const float4*)&hb[(i) * 4];                          \
       z0 = fmaf(P##i##x, hv.x, z0); z1 = fmaf(P##i##y, hv.y, z1);        \
       z2 = fmaf(P##i##z, hv.z, z2); z3 = fmaf(P##i##w, hv.w, z3); }

// 4-chain dot: weight quad i applied to 4 h banks (stride 40 floats).
// All h addresses are wave-uniform -> LDS broadcast, conflict-free.
#define DOT4Q(P, i)                                                       \
    {   float4 hA = *(const float4*)&hbb[0 * 40 + (i) * 4];               \
        A0 = fmaf(P##i##x, hA.x, A0); A1 = fmaf(P##i##y, hA.y, A1);       \
        A2 = fmaf(P##i##z, hA.z, A2); A3 = fmaf(P##i##w, hA.w, A3);       \
        float4 hB = *(const float4*)&hbb[1 * 40 + (i) * 4];               \
        B0 = fmaf(P##i##x, hB.x, B0); B1 = fmaf(P##i##y, hB.y, B1);       \
        B2 = fmaf(P##i##z, hB.z, B2); B3 = fmaf(P##i##w, hB.w, B3);       \
        float4 hC = *(const float4*)&hbb[2 * 40 + (i) * 4];               \
        C0 = fmaf(P##i##x, hC.x, C0); C1 = fmaf(P##i##y, hC.y, C1);       \
        C2 = fmaf(P##i##z, hC.z, C2); C3 = fmaf(P##i##w, hC.w, C3);       \
        float4 hD = *(const float4*)&hbb[3 * 40 + (i) * 4];               \
        D0 = fmaf(P##i##x, hD.x, D0); D1 = fmaf(P##i##y, hD.y, D1);       \
        D2 = fmaf(P##i##z, hD.z, D2); D3 = fmaf(P##i##w, hD.w, D3); }

// array-based dots (fallback kernel only)
#define DOT36(W, H, Z0, Z1, Z2, Z3)                        \
    do {                                                   \
        _Pragma("unroll") for (int _k = 0; _k < 9; ++_k) { \
            float4 hv = *(const float4*)&(H)[_k * 4];      \
            Z0 = fmaf((W)[_k * 4 + 0], hv.x, Z0);          \
            Z1 = fmaf((W)[_k * 4 + 1], hv.y, Z1);          \
            Z2 = fmaf((W)[_k * 4 + 2], hv.z, Z2);          \
            Z3 = fmaf((W)[_k * 4 + 3], hv.w, Z3);          \
        }                                                  \
    } while (0)

#define DOT72(W, H, Z0, Z1, Z2, Z3)                         \
    do {                                                    \
        _Pragma("unroll") for (int _k = 0; _k < 18; ++_k) { \
            float4 hv = *(const float4*)&(H)[_k * 4];       \
            Z0 = fmaf((W)[_k * 4 + 0], hv.x, Z0);           \
            Z1 = fmaf((W)[_k * 4 + 1], hv.y, Z1);           \
            Z2 = fmaf((W)[_k * 4 + 2], hv.z, Z2);           \
            Z3 = fmaf((W)[_k * 4 + 3], hv.w, Z3);           \
        }                                                   \
    } while (0)

// ============ K1: layer-0 REVERSE scan, full batch -> h0r (151 MB ws) ========
#define SG1 4
#define NTK1 (SG1 * G4)   // 576
__global__ __launch_bounds__(NTK1) void l0rev_kernel(
    const float* __restrict__ x,
    const float* __restrict__ Wih, const float* __restrict__ Whh,
    const float* __restrict__ bih, const float* __restrict__ bhh,
    float* __restrict__ h0r)
{
    const int tid = threadIdx.x;
    const int cc  = tid / G4;
    const int g   = tid % G4;
    const int b   = blockIdx.x * SG1 + cc;

    __shared__ float xs[SG1][TT];
    __shared__ float hs[SG1][40];
    __shared__ float zs[SG1][G4];

    for (int i = g; i < TT; i += G4) xs[cc][i] = x[(size_t)b * TT + i];

    REP9(DECLQ, R)
    {
        const float4* wp = (const float4*)(Whh + g * Hn);
        REP9(LOADQ, R)
    }
    float wx   = Wih[g];
    float bias = bih[g] + bhh[g];
    REP9(PINQ, R)
    asm volatile("" : "+v"(wx), "+v"(bias));

    if (g < 40) hs[cc][g] = 0.0f;
    float c = 0.0f;
    __syncthreads();

    float* dst = h0r + (size_t)b * TT * Hn;

    for (int s = 0; s < TT; ++s) {
        const int t = TT - 1 - s;
        float z0 = fmaf(xs[cc][t], wx, bias), z1 = 0.f, z2 = 0.f, z3 = 0.f;
        {
            const float* hb = hs[cc];
            REP9(FMAQ, R)
        }
        zs[cc][g] = (z0 + z1) + (z2 + z3);
        __syncthreads();
        if (g < Hn) {
            float zi = zs[cc][g], zf = zs[cc][g + 36], zg = zs[cc][g + 72], zo = zs[cc][g + 108];
            c = sigf(zf) * c + sigf(zi) * tanh_fast(zg);
            float h = sigf(zo) * tanh_fast(c);
            hs[cc][g] = h;
            dst[(size_t)t * Hn + g] = h;
        }
        __syncthreads();
    }
}

// ===== K2: skewed fusion, 4 chains/block, per-thread weights amortized 4x ====
// Groups: 0:F(Whh0f->h0f)  1:L(Wih1f lo . h0f)  2:L(Wih1f hi . h0r)  3:L(Whh1f . h1)
#define SG2 4
#define NT2 576
__global__ __launch_bounds__(NT2) void fused_fl_kernel(
    const float* __restrict__ x,
    const float* __restrict__ Wih0f, const float* __restrict__ Whh0f,
    const float* __restrict__ bih0f, const float* __restrict__ bhh0f,
    const float* __restrict__ Wih1f, const float* __restrict__ Whh1f,
    const float* __restrict__ bih1f, const float* __restrict__ bhh1f,
    const float* __restrict__ Wih1r,
    const float* __restrict__ bih1r, const float* __restrict__ bhh1r,
    const float* __restrict__ fcW, const float* __restrict__ fcb,
    const float* __restrict__ h0r,
    float* __restrict__ out)
{
    const int tid  = threadIdx.x;
    const int gp   = tid / G4;     // dot group 0..3
    const int g    = tid % G4;     // gate row
    const int cc2  = g / Hn;       // combine-lane chain (0..3)
    const int ii   = g % Hn;       // combine-lane unit  (0..35)
    const int base = blockIdx.x * SG2;

    __shared__ float xs[SG2][TT + 2];
    __shared__ float h0f[2][SG2][40];
    __shared__ float h0rs[2][SG2][40];
    __shared__ float h1s[SG2][40];
    __shared__ float zF[SG2][G4];
    __shared__ float zL[3][SG2][G4];
    __shared__ float red[SG2][40];

    for (int i = tid; i < SG2 * (TT + 2); i += NT2) {
        int c = i / (TT + 2), t = i % (TT + 2);
        xs[c][t] = (t < TT) ? x[(size_t)(base + c) * TT + t] : 0.0f;
    }
    for (int i = tid; i < 2 * SG2 * 40; i += NT2) {
        (&h0f[0][0][0])[i] = 0.0f;
        (&h0rs[0][0][0])[i] = 0.0f;
    }
    for (int i = tid; i < SG2 * 40; i += NT2) (&h1s[0][0])[i] = 0.0f;

    const float* wbase = (gp == 0) ? (Whh0f + g * Hn)
                       : (gp == 1) ? (Wih1f + g * 72)
                       : (gp == 2) ? (Wih1f + g * 72 + 36)
                                   : (Whh1f + g * Hn);
    REP9(DECLQ, W)
    {
        const float4* wp = (const float4*)wbase;
        REP9(LOADQ, W)
    }
    float wx0  = (gp == 0) ? Wih0f[g] : 0.0f;
    float bsum = (gp == 0) ? (bih0f[g] + bhh0f[g])
               : (gp == 3) ? (bih1f[g] + bhh1f[g]) : 0.0f;
    REP9(PINQ, W)
    asm volatile("" : "+v"(wx0), "+v"(bsum));

    const float* srow = h0r + (size_t)(base + cc2) * TT * Hn + ii;   // gp2 stream
    float c0 = 0.0f, c1 = 0.0f;
    __syncthreads();

    // ---- prologue: h0f(0) = step(h=0, x0); gp2 stages h0r(0), prefetch h0r(1)
    float rv = 0.0f;
    if (gp == 0) {
#pragma unroll
        for (int c = 0; c < SG2; ++c) zF[c][g] = fmaf(xs[c][0], wx0, bsum);
    } else if (gp == 2) {
        h0rs[0][cc2][ii] = srow[0];
        rv = srow[Hn];                        // h0r(1)
    }
    __syncthreads();
    if (gp == 0) {
        float zi = zF[cc2][ii], zg = zF[cc2][ii + 72], zo = zF[cc2][ii + 108];
        c0 = sigf(zi) * tanh_fast(zg);        // c=0 start: forget term vanishes
        h0f[0][cc2][ii] = sigf(zo) * tanh_fast(c0);
    }
    __syncthreads();

    int cur = 0;
    for (int t = 0; t < TT; ++t) {
        float rv2 = (gp == 2 && t + 2 < TT) ? srow[(size_t)(t + 2) * Hn] : 0.0f;

        const float* hbb = (gp <= 1) ? &h0f[cur][0][0]
                         : (gp == 2) ? &h0rs[cur][0][0] : &h1s[0][0];
        float A0, B0, C0, D0;
        if (gp == 0) {
            A0 = fmaf(xs[0][t + 1], wx0, bsum);
            B0 = fmaf(xs[1][t + 1], wx0, bsum);
            C0 = fmaf(xs[2][t + 1], wx0, bsum);
            D0 = fmaf(xs[3][t + 1], wx0, bsum);
        } else {
            A0 = bsum; B0 = bsum; C0 = bsum; D0 = bsum;   // bsum=0 for gp1/2
        }
        float A1 = 0.f, A2 = 0.f, A3 = 0.f, B1 = 0.f, B2 = 0.f, B3 = 0.f;
        float C1 = 0.f, C2 = 0.f, C3 = 0.f, D1 = 0.f, D2 = 0.f, D3 = 0.f;

        REP9(DOT4Q, W)

        float zA = (A0 + A1) + (A2 + A3);
        float zB = (B0 + B1) + (B2 + B3);
        float zC = (C0 + C1) + (C2 + C3);
        float zD = (D0 + D1) + (D2 + D3);
        if (gp == 0) {
            zF[0][g] = zA; zF[1][g] = zB; zF[2][g] = zC; zF[3][g] = zD;
        } else {
            float* zt = &zL[gp - 1][0][0];
            zt[0 * G4 + g] = zA; zt[1 * G4 + g] = zB;
            zt[2 * G4 + g] = zC; zt[3 * G4 + g] = zD;
        }
        __syncthreads();

        if (gp == 0) {
            if (t + 1 < TT) {                  // produce h0f(t+1)
                float zi = zF[cc2][ii],       zf = zF[cc2][ii + 36];
                float zg = zF[cc2][ii + 72],  zo = zF[cc2][ii + 108];
                c0 = sigf(zf) * c0 + sigf(zi) * tanh_fast(zg);
                h0f[cur ^ 1][cc2][ii] = sigf(zo) * tanh_fast(c0);
            }
        } else if (gp == 3) {                  // produce h1(t)
            float zi = zL[0][cc2][ii]       + zL[1][cc2][ii]       + zL[2][cc2][ii];
            float zf = zL[0][cc2][ii + 36]  + zL[1][cc2][ii + 36]  + zL[2][cc2][ii + 36];
            float zg = zL[0][cc2][ii + 72]  + zL[1][cc2][ii + 72]  + zL[2][cc2][ii + 72];
            float zo = zL[0][cc2][ii + 108] + zL[1][cc2][ii + 108] + zL[2][cc2][ii + 108];
            c1 = sigf(zf) * c1 + sigf(zi) * tanh_fast(zg);
            h1s[cc2][ii] = sigf(zo) * tanh_fast(c1);
        } else if (gp == 2 && t + 1 < TT) {
            h0rs[cur ^ 1][cc2][ii] = rv;       // stage h0r(t+1)
        }
        __syncthreads();
        rv = rv2;
        if (t + 1 < TT) cur ^= 1;
    }

    // ---- tail: L1 reverse single step at t=T-1 (h0=c0=0) + FC ----
    {   // thread (chain=gp, row=g): full 72-dim dot vs [h0f | h0r](T-1)
        float zR = bih1r[g] + bhh1r[g];
        const float* wr = Wih1r + g * 72;
#pragma unroll
        for (int k = 0; k < Hn; ++k) zR = fmaf(wr[k],      h0f[cur][gp][k],  zR);
#pragma unroll
        for (int k = 0; k < Hn; ++k) zR = fmaf(wr[36 + k], h0rs[cur][gp][k], zR);
        zF[gp][g] = zR;
    }
    __syncthreads();
    if (tid < SG2 * Hn) {
        int c = tid / Hn, i = tid % Hn;
        float zi = zF[c][i], zg = zF[c][i + 72], zo = zF[c][i + 108];
        float cR = sigf(zi) * tanh_fast(zg);   // c0=0: forget term vanishes
        float hR = sigf(zo) * tanh_fast(cR);
        red[c][i] = fcW[36 + i] * hR + fcW[i] * h1s[c][i];
    }
    __syncthreads();
    if (tid < SG2) {
        float s2 = fcb[0];
        for (int j = 0; j < Hn; ++j) s2 += red[tid][j];
        out[base + tid] = s2;
    }
}

// ================= FALLBACK PATH (zero workspace, ckpt/recompute) ============
__global__ __launch_bounds__(G4, 1) void fused_all_kernel(
    const float* __restrict__ x,
    const float* __restrict__ Wih0f, const float* __restrict__ Whh0f,
    const float* __restrict__ bih0f, const float* __restrict__ bhh0f,
    const float* __restrict__ Wih0r, const float* __restrict__ Whh0r,
    const float* __restrict__ bih0r, const float* __restrict__ bhh0r,
    const float* __restrict__ Wih1f, const float* __restrict__ Whh1f,
    const float* __restrict__ bih1f, const float* __restrict__ bhh1f,
    const float* __restrict__ Wih1r,
    const float* __restrict__ bih1r, const float* __restrict__ bhh1r,
    const float* __restrict__ fcW, const float* __restrict__ fcb,
    float* __restrict__ out)
{
    const int g = threadIdx.x;
    const int b = blockIdx.x;

    __shared__ float xs[TT];
    __shared__ float cbuf[64][Hn];
    __shared__ float ckpt_h[8][Hn], ckpt_c[8][Hn];
    __shared__ float hr[40], h0s[80], hs1[40], zs[G4], red[40];

    for (int i = g; i < TT; i += G4) xs[i] = x[(size_t)b * TT + i];

    float wr[Hn], wf[Hn];
#pragma unroll
    for (int k = 0; k < Hn; ++k) wr[k] = Whh0r[g * Hn + k];
#pragma unroll
    for (int k = 0; k < Hn; ++k) wf[k] = Whh0f[g * Hn + k];
    const float wxr = Wih0r[g], br = bih0r[g] + bhh0r[g];
    const float wxf = Wih0f[g], bf = bih0f[g] + bhh0f[g];
    float w1i[72];
#pragma unroll
    for (int k = 0; k < 72; ++k) w1i[k] = Wih1f[g * 72 + k];
    float w1h[Hn];
#pragma unroll
    for (int k = 0; k < Hn; ++k) w1h[k] = Whh1f[g * Hn + k];
    const float b1 = bih1f[g] + bhh1f[g];

    if (g < Hn) hr[g] = 0.0f;
    float cr = 0.0f;
    __syncthreads();
    for (int s = 0; s < TT; ++s) {
        const int t = TT - 1 - s;
        if ((t & 63) == 63 && g < Hn) { ckpt_h[t >> 6][g] = hr[g]; ckpt_c[t >> 6][g] = cr; }
        float z0 = fmaf(xs[t], wxr, br), z1 = 0.f, z2 = 0.f, z3 = 0.f;
        DOT36(wr, hr, z0, z1, z2, z3);
        zs[g] = (z0 + z1) + (z2 + z3);
        __syncthreads();
        if (g < Hn) {
            float zi = zs[g], zf = zs[g + 36], zg = zs[g + 72], zo = zs[g + 108];
            cr = sigf(zf) * cr + sigf(zi) * tanh_fast(zg);
            hr[g] = sigf(zo) * tanh_fast(cr);
        }
        __syncthreads();
    }

    if (g < Hn) { h0s[g] = 0.0f; hs1[g] = 0.0f; }
    float c0 = 0.0f, c1 = 0.0f;
    __syncthreads();

    for (int m = 0; m < 8; ++m) {
        if (g < Hn) { hr[g] = ckpt_h[m][g]; cr = ckpt_c[m][g]; }
        __syncthreads();
        for (int j = 0; j < 64; ++j) {
            const int t = m * 64 + 63 - j;
            float z0 = fmaf(xs[t], wxr, br), z1 = 0.f, z2 = 0.f, z3 = 0.f;
            DOT36(wr, hr, z0, z1, z2, z3);
            zs[g] = (z0 + z1) + (z2 + z3);
            __syncthreads();
            if (g < Hn) {
                float zi = zs[g], zf = zs[g + 36], zg = zs[g + 72], zo = zs[g + 108];
                cr = sigf(zf) * cr + sigf(zi) * tanh_fast(zg);
                float h = sigf(zo) * tanh_fast(cr);
                hr[g] = h;
                cbuf[t & 63][g] = h;
            }
            __syncthreads();
        }
        for (int j = 0; j < 64; ++j) {
            const int t = m * 64 + j;
            float z0 = fmaf(xs[t], wxf, bf), z1 = 0.f, z2 = 0.f, z3 = 0.f;
            DOT36(wf, h0s, z0, z1, z2, z3);
            zs[g] = (z0 + z1) + (z2 + z3);
            __syncthreads();
            if (g < Hn) {
                float zi = zs[g], zf = zs[g + 36], zg = zs[g + 72], zo = zs[g + 108];
                c0 = sigf(zf) * c0 + sigf(zi) * tanh_fast(zg);
                h0s[g] = sigf(zo) * tanh_fast(c0);
            } else if (g < 72) {
                h0s[g] = cbuf[j][g - 36];
            }
            __syncthreads();
            float y0 = b1, y1 = 0.f, y2 = 0.f, y3 = 0.f;
            DOT72(w1i, h0s, y0, y1, y2, y3);
            DOT36(w1h, hs1, y0, y1, y2, y3);
            zs[g] = (y0 + y1) + (y2 + y3);
            __syncthreads();
            if (g < Hn) {
                float zi = zs[g], zf = zs[g + 36], zg = zs[g + 72], zo = zs[g + 108];
                c1 = sigf(zf) * c1 + sigf(zi) * tanh_fast(zg);
                hs1[g] = sigf(zo) * tanh_fast(c1);
            }
            __syncthreads();
        }
    }

    float zR = bih1r[g] + bhh1r[g];
#pragma unroll
    for (int k = 0; k < 72; ++k) zR = fmaf(Wih1r[g * 72 + k], h0s[k], zR);
    zs[g] = zR;
    __syncthreads();
    if (g < Hn) {
        float zi = zs[g], zg = zs[g + 72], zo = zs[g + 108];
        float c  = sigf(zi) * tanh_fast(zg);
        float hrv = sigf(zo) * tanh_fast(c);
        red[g] = fcW[36 + g] * hrv + fcW[g] * hs1[g];
    }
    __syncthreads();
    if (g == 0) {
        float s = fcb[0];
        for (int j = 0; j < Hn; ++j) s += red[j];
        out[b] = s;
    }
}

extern "C" void kernel_launch(void* const* d_in, const int* in_sizes, int n_in,
                              void* d_out, int out_size, void* d_ws, size_t ws_size,
                              hipStream_t stream)
{
    const float* x     = (const float*)d_in[0];
    const float* Wih0f = (const float*)d_in[1];
    const float* Whh0f = (const float*)d_in[2];
    const float* bih0f = (const float*)d_in[3];
    const float* bhh0f = (const float*)d_in[4];
    const float* Wih0r = (const float*)d_in[5];
    const float* Whh0r = (const float*)d_in[6];
    const float* bih0r = (const float*)d_in[7];
    const float* bhh0r = (const float*)d_in[8];
    const float* Wih1f = (const float*)d_in[9];
    const float* Whh1f = (const float*)d_in[10];
    const float* bih1f = (const float*)d_in[11];
    const float* bhh1f = (const float*)d_in[12];
    const float* Wih1r = (const float*)d_in[13];
    const float* bih1r = (const float*)d_in[15];
    const float* bhh1r = (const float*)d_in[16];
    const float* fcW   = (const float*)d_in[17];
    const float* fcb   = (const float*)d_in[18];

    const size_t need = (size_t)BB * TT * Hn * sizeof(float);   // 151 MB (known-safe)
    if (d_ws != nullptr && ws_size >= need) {
        float* h0r = (float*)d_ws;
        l0rev_kernel<<<BB / SG1, NTK1, 0, stream>>>(x, Wih0r, Whh0r, bih0r, bhh0r, h0r);
        fused_fl_kernel<<<BB / SG2, NT2, 0, stream>>>(
            x, Wih0f, Whh0f, bih0f, bhh0f, Wih1f, Whh1f, bih1f, bhh1f,
            Wih1r, bih1r, bhh1r, fcW, fcb, h0r, (float*)d_out);
    } else {
        fused_all_kernel<<<BB, G4, 0, stream>>>(
            x, Wih0f, Whh0f, bih0f, bhh0f, Wih0r, Whh0r, bih0r, bhh0r,
            Wih1f, Whh1f, bih1f, bhh1f, Wih1r, bih1r, bhh1r, fcW, fcb,
            (float*)d_out);
    }
}

// Round 14
// 2004.972 us; speedup vs baseline: 2.9711x; 1.0156x over previous
//
#include <hip/hip_runtime.h>
#include <cstdint>

#define Hn 36
#define G4 144          // 4*H gate rows
#define TT 512
#define BB 2048

__device__ __forceinline__ float sigf(float x) { return 1.0f / (1.0f + __expf(-x)); }
__device__ __forceinline__ float tanh_fast(float x) {
    float e = __expf(2.0f * x);          // exact +-1 limits via over/underflow
    return 1.0f - 2.0f / (e + 1.0f);
}

// ---- K1 named-register weight quads (K1 verified at ~420us; untouched) ----
#define REP9(M, P)  M(P,0) M(P,1) M(P,2) M(P,3) M(P,4) M(P,5) M(P,6) M(P,7) M(P,8)
#define DECLQ(P, i) float P##i##x, P##i##y, P##i##z, P##i##w;
#define LOADQ(P, i) { float4 _t = wp[i]; P##i##x = _t.x; P##i##y = _t.y; P##i##z = _t.z; P##i##w = _t.w; }
#define PINQ(P, i)  asm volatile("" : "+v"(P##i##x), "+v"(P##i##y), "+v"(P##i##z), "+v"(P##i##w));
#define FMAQ(P, i)                                                        \
    {  float4 hv = *(const float4*)&hb[(i) * 4];                          \
       z0 = fmaf(P##i##x, hv.x, z0); z1 = fmaf(P##i##y, hv.y, z1);        \
       z2 = fmaf(P##i##z, hv.z, z2); z3 = fmaf(P##i##w, hv.w, z3); }

// array-based dots (fallback kernel only)
#define DOT36(W, H, Z0, Z1, Z2, Z3)                        \
    do {                                                   \
        _Pragma("unroll") for (int _k = 0; _k < 9; ++_k) { \
            float4 hv = *(const float4*)&(H)[_k * 4];      \
            Z0 = fmaf((W)[_k * 4 + 0], hv.x, Z0);          \
            Z1 = fmaf((W)[_k * 4 + 1], hv.y, Z1);          \
            Z2 = fmaf((W)[_k * 4 + 2], hv.z, Z2);          \
            Z3 = fmaf((W)[_k * 4 + 3], hv.w, Z3);          \
        }                                                  \
    } while (0)

#define DOT72(W, H, Z0, Z1, Z2, Z3)                         \
    do {                                                    \
        _Pragma("unroll") for (int _k = 0; _k < 18; ++_k) { \
            float4 hv = *(const float4*)&(H)[_k * 4];       \
            Z0 = fmaf((W)[_k * 4 + 0], hv.x, Z0);           \
            Z1 = fmaf((W)[_k * 4 + 1], hv.y, Z1);           \
            Z2 = fmaf((W)[_k * 4 + 2], hv.z, Z2);           \
            Z3 = fmaf((W)[_k * 4 + 3], hv.w, Z3);           \
        }                                                   \
    } while (0)

// ============ K1: layer-0 REVERSE scan, full batch -> h0r (151 MB ws) ========
#define SG1 4
#define NTK1 (SG1 * G4)   // 576
__global__ __launch_bounds__(NTK1) void l0rev_kernel(
    const float* __restrict__ x,
    const float* __restrict__ Wih, const float* __restrict__ Whh,
    const float* __restrict__ bih, const float* __restrict__ bhh,
    float* __restrict__ h0r)
{
    const int tid = threadIdx.x;
    const int cc  = tid / G4;
    const int g   = tid % G4;
    const int b   = blockIdx.x * SG1 + cc;

    __shared__ float xs[SG1][TT];
    __shared__ float hs[SG1][40];
    __shared__ float zs[SG1][G4];

    for (int i = g; i < TT; i += G4) xs[cc][i] = x[(size_t)b * TT + i];

    REP9(DECLQ, R)
    {
        const float4* wp = (const float4*)(Whh + g * Hn);
        REP9(LOADQ, R)
    }
    float wx   = Wih[g];
    float bias = bih[g] + bhh[g];
    REP9(PINQ, R)
    asm volatile("" : "+v"(wx), "+v"(bias));

    if (g < 40) hs[cc][g] = 0.0f;
    float c = 0.0f;
    __syncthreads();

    float* dst = h0r + (size_t)b * TT * Hn;

    for (int s = 0; s < TT; ++s) {
        const int t = TT - 1 - s;
        float z0 = fmaf(xs[cc][t], wx, bias), z1 = 0.f, z2 = 0.f, z3 = 0.f;
        {
            const float* hb = hs[cc];
            REP9(FMAQ, R)
        }
        zs[cc][g] = (z0 + z1) + (z2 + z3);
        __syncthreads();
        if (g < Hn) {
            float zi = zs[cc][g], zf = zs[cc][g + 36], zg = zs[cc][g + 72], zo = zs[cc][g + 108];
            c = sigf(zf) * c + sigf(zi) * tanh_fast(zg);
            float h = sigf(zo) * tanh_fast(c);
            hs[cc][g] = h;
            dst[(size_t)t * Hn + g] = h;
        }
        __syncthreads();
    }
}

// ====== K2: skewed fusion, 8 chains/block, LDS weight tables (no scratch) ====
// Dot groups: 0:Whh0f.h0f(+x)  1:Wih1f[:, :36].h0f  2:Wih1f[:, 36:].h0r  3:Whh1f.h1
// Combine roles: tid<288 -> L0 state (chain ca, unit ia); tid>=288 -> L1 state + h0r staging.
#define SG2  8
#define NT2  576
#define NB2  (BB / SG2)   // 256 blocks = 1/CU
#define W1ST 76           // Wih1f row stride in LDS (76%32=12 -> bank-balanced b128)

// 8-chain dot: weight quad i (per-lane LDS row) x 8 broadcast h banks (stride 40)
#define DOT8Q(i)                                                              \
    {   float4 wq = *(const float4*)&wrow[(i) * 4];                           \
        float4 hq;                                                            \
        hq = *(const float4*)&hbb[0 * 40 + (i) * 4];                          \
        A0 = fmaf(wq.x, hq.x, A0); A1 = fmaf(wq.y, hq.y, A1);                 \
        A2 = fmaf(wq.z, hq.z, A2); A3 = fmaf(wq.w, hq.w, A3);                 \
        hq = *(const float4*)&hbb[1 * 40 + (i) * 4];                          \
        B0 = fmaf(wq.x, hq.x, B0); B1 = fmaf(wq.y, hq.y, B1);                 \
        B2 = fmaf(wq.z, hq.z, B2); B3 = fmaf(wq.w, hq.w, B3);                 \
        hq = *(const float4*)&hbb[2 * 40 + (i) * 4];                          \
        C0 = fmaf(wq.x, hq.x, C0); C1 = fmaf(wq.y, hq.y, C1);                 \
        C2 = fmaf(wq.z, hq.z, C2); C3 = fmaf(wq.w, hq.w, C3);                 \
        hq = *(const float4*)&hbb[3 * 40 + (i) * 4];                          \
        D0 = fmaf(wq.x, hq.x, D0); D1 = fmaf(wq.y, hq.y, D1);                 \
        D2 = fmaf(wq.z, hq.z, D2); D3 = fmaf(wq.w, hq.w, D3);                 \
        hq = *(const float4*)&hbb[4 * 40 + (i) * 4];                          \
        E0 = fmaf(wq.x, hq.x, E0); E1 = fmaf(wq.y, hq.y, E1);                 \
        E2 = fmaf(wq.z, hq.z, E2); E3 = fmaf(wq.w, hq.w, E3);                 \
        hq = *(const float4*)&hbb[5 * 40 + (i) * 4];                          \
        F0 = fmaf(wq.x, hq.x, F0); F1 = fmaf(wq.y, hq.y, F1);                 \
        F2 = fmaf(wq.z, hq.z, F2); F3 = fmaf(wq.w, hq.w, F3);                 \
        hq = *(const float4*)&hbb[6 * 40 + (i) * 4];                          \
        G0 = fmaf(wq.x, hq.x, G0); G1 = fmaf(wq.y, hq.y, G1);                 \
        G2 = fmaf(wq.z, hq.z, G2); G3 = fmaf(wq.w, hq.w, G3);                 \
        hq = *(const float4*)&hbb[7 * 40 + (i) * 4];                          \
        H0 = fmaf(wq.x, hq.x, H0); H1 = fmaf(wq.y, hq.y, H1);                 \
        H2 = fmaf(wq.z, hq.z, H2); H3 = fmaf(wq.w, hq.w, H3); }

__global__ __launch_bounds__(NT2) void fused_fl_kernel(
    const float* __restrict__ x,
    const float* __restrict__ Wih0f, const float* __restrict__ Whh0f,
    const float* __restrict__ bih0f, const float* __restrict__ bhh0f,
    const float* __restrict__ Wih1f, const float* __restrict__ Whh1f,
    const float* __restrict__ bih1f, const float* __restrict__ bhh1f,
    const float* __restrict__ Wih1r,
    const float* __restrict__ bih1r, const float* __restrict__ bhh1r,
    const float* __restrict__ fcW, const float* __restrict__ fcb,
    const float* __restrict__ h0r,
    float* __restrict__ out)
{
    const int tid  = threadIdx.x;
    const int gp   = tid / G4;     // dot group 0..3
    const int g    = tid % G4;     // gate row
    const int base = blockIdx.x * SG2;
    // combine roles
    const int ca = tid / Hn;             // L0 chain (tid<288)
    const int ia = tid % Hn;             // L0 unit
    const int ct = tid - 288;            // L1 role index
    const int cb = (ct >= 0) ? ct / Hn : 0;
    const int ib = (ct >= 0) ? ct % Hn : 0;

    __shared__ float wt0[G4 * 36];       // Whh0f (20.7 KB)  stride 36: balanced
    __shared__ float wt1[G4 * W1ST];     // Wih1f (43.8 KB)  stride 76: balanced
    __shared__ float wt3[G4 * 36];       // Whh1f (20.7 KB)
    __shared__ float xs[SG2][TT + 2];    // 16.4 KB
    __shared__ float h0f[2][SG2][40];
    __shared__ float h0rs[2][SG2][40];
    __shared__ float h1s[SG2][40];
    __shared__ float zF[SG2][G4];        // 4.6 KB
    __shared__ float zL[3][SG2][G4];     // 13.8 KB
    __shared__ float red[SG2][Hn];

    // ---------------- one-time staging ----------------
    for (int i = tid; i < G4 * 36; i += NT2) wt0[i] = Whh0f[i];
    for (int i = tid; i < G4 * 72; i += NT2)
        wt1[(i / 72) * W1ST + (i % 72)] = Wih1f[i];
    for (int i = tid; i < G4 * 36; i += NT2) wt3[i] = Whh1f[i];
    for (int i = tid; i < SG2 * (TT + 2); i += NT2) {
        int c = i / (TT + 2), t = i % (TT + 2);
        xs[c][t] = (t < TT) ? x[(size_t)(base + c) * TT + t] : 0.0f;
    }
    for (int i = tid; i < 2 * SG2 * 40; i += NT2) {
        (&h0f[0][0][0])[i] = 0.0f;
        (&h0rs[0][0][0])[i] = 0.0f;
    }
    for (int i = tid; i < SG2 * 40; i += NT2) (&h1s[0][0])[i] = 0.0f;

    const float* wrow = (gp == 0) ? &wt0[g * 36]
                      : (gp == 1) ? &wt1[g * W1ST]
                      : (gp == 2) ? &wt1[g * W1ST + 36]
                                  : &wt3[g * 36];
    const float wx0  = (gp == 0) ? Wih0f[g] : 0.0f;
    const float bsum = (gp == 0) ? (bih0f[g] + bhh0f[g])
                     : (gp == 3) ? (bih1f[g] + bhh1f[g]) : 0.0f;

    const float* srow = h0r + (size_t)(base + cb) * TT * Hn + ib;   // L1-role h0r stream
    float c0 = 0.0f, c1 = 0.0f, rvv = 0.0f;
    __syncthreads();

    // ---- prologue: h0f(0) = step(h=0, x0); stage h0r(0); prefetch h0r(1) ----
    if (gp == 0) {
#pragma unroll
        for (int c = 0; c < SG2; ++c) zF[c][g] = fmaf(xs[c][0], wx0, bsum);
    }
    if (ct >= 0) {
        h0rs[0][cb][ib] = srow[0];
        rvv = srow[Hn];
    }
    __syncthreads();
    if (tid < 288) {
        float zi = zF[ca][ia], zg = zF[ca][ia + 72], zo = zF[ca][ia + 108];
        c0 = sigf(zi) * tanh_fast(zg);        // c=0 start: forget term vanishes
        h0f[0][ca][ia] = sigf(zo) * tanh_fast(c0);
    }
    __syncthreads();

    int cur = 0;
    for (int t = 0; t < TT; ++t) {
        float rv2 = (ct >= 0 && t + 2 < TT) ? srow[(size_t)(t + 2) * Hn] : 0.0f;

        const float* hbb = (gp <= 1) ? &h0f[cur][0][0]
                         : (gp == 2) ? &h0rs[cur][0][0] : &h1s[0][0];
        float A0, B0, C0, D0, E0, F0, G0, H0;
        if (gp == 0) {
            A0 = fmaf(xs[0][t + 1], wx0, bsum);
            B0 = fmaf(xs[1][t + 1], wx0, bsum);
            C0 = fmaf(xs[2][t + 1], wx0, bsum);
            D0 = fmaf(xs[3][t + 1], wx0, bsum);
            E0 = fmaf(xs[4][t + 1], wx0, bsum);
            F0 = fmaf(xs[5][t + 1], wx0, bsum);
            G0 = fmaf(xs[6][t + 1], wx0, bsum);
            H0 = fmaf(xs[7][t + 1], wx0, bsum);
        } else {
            A0 = bsum; B0 = bsum; C0 = bsum; D0 = bsum;   // bsum=0 for gp1/2
            E0 = bsum; F0 = bsum; G0 = bsum; H0 = bsum;
        }
        float A1 = 0.f, A2 = 0.f, A3 = 0.f, B1 = 0.f, B2 = 0.f, B3 = 0.f;
        float C1 = 0.f, C2 = 0.f, C3 = 0.f, D1 = 0.f, D2 = 0.f, D3 = 0.f;
        float E1 = 0.f, E2 = 0.f, E3 = 0.f, F1 = 0.f, F2 = 0.f, F3 = 0.f;
        float G1 = 0.f, G2 = 0.f, G3 = 0.f, H1 = 0.f, H2 = 0.f, H3 = 0.f;

        DOT8Q(0) DOT8Q(1) DOT8Q(2) DOT8Q(3) DOT8Q(4)
        DOT8Q(5) DOT8Q(6) DOT8Q(7) DOT8Q(8)

        float zA = (A0 + A1) + (A2 + A3), zB = (B0 + B1) + (B2 + B3);
        float zC = (C0 + C1) + (C2 + C3), zD = (D0 + D1) + (D2 + D3);
        float zE = (E0 + E1) + (E2 + E3), zF_ = (F0 + F1) + (F2 + F3);
        float zG = (G0 + G1) + (G2 + G3), zH = (H0 + H1) + (H2 + H3);
        float* zt = (gp == 0) ? &zF[0][0] : &zL[gp - 1][0][0];
        zt[0 * G4 + g] = zA; zt[1 * G4 + g] = zB; zt[2 * G4 + g] = zC;
        zt[3 * G4 + g] = zD; zt[4 * G4 + g] = zE; zt[5 * G4 + g] = zF_;
        zt[6 * G4 + g] = zG; zt[7 * G4 + g] = zH;
        __syncthreads();

        if (tid < 288) {                       // L0 combine -> h0f(t+1)
            if (t + 1 < TT) {
                float zi = zF[ca][ia],       zf = zF[ca][ia + 36];
                float zg = zF[ca][ia + 72],  zo = zF[ca][ia + 108];
                c0 = sigf(zf) * c0 + sigf(zi) * tanh_fast(zg);
                h0f[cur ^ 1][ca][ia] = sigf(zo) * tanh_fast(c0);
            }
        } else {                               // L1 combine -> h1(t); stage h0r(t+1)
            float zi = zL[0][cb][ib]       + zL[1][cb][ib]       + zL[2][cb][ib];
            float zf = zL[0][cb][ib + 36]  + zL[1][cb][ib + 36]  + zL[2][cb][ib + 36];
            float zg = zL[0][cb][ib + 72]  + zL[1][cb][ib + 72]  + zL[2][cb][ib + 72];
            float zo = zL[0][cb][ib + 108] + zL[1][cb][ib + 108] + zL[2][cb][ib + 108];
            c1 = sigf(zf) * c1 + sigf(zi) * tanh_fast(zg);
            h1s[cb][ib] = sigf(zo) * tanh_fast(c1);
            if (t + 1 < TT) h0rs[cur ^ 1][cb][ib] = rvv;
        }
        __syncthreads();
        rvv = rv2;
        if (t + 1 < TT) cur ^= 1;
    }

    // ---- tail: L1 reverse single step at t=T-1 (h0=c0=0) + FC ----
    {   // each gp handles 2 chains: full 72-dim dot vs [h0f | h0r](T-1)
#pragma unroll
        for (int sub = 0; sub < 2; ++sub) {
            const int cc = gp * 2 + sub;
            float zR = bih1r[g] + bhh1r[g];
            const float* wr = Wih1r + g * 72;
#pragma unroll
            for (int k = 0; k < Hn; ++k) zR = fmaf(wr[k],      h0f[cur][cc][k],  zR);
#pragma unroll
            for (int k = 0; k < Hn; ++k) zR = fmaf(wr[36 + k], h0rs[cur][cc][k], zR);
            zF[cc][g] = zR;
        }
    }
    __syncthreads();
    if (tid < 288) {
        float zi = zF[ca][ia], zg = zF[ca][ia + 72], zo = zF[ca][ia + 108];
        float cR = sigf(zi) * tanh_fast(zg);   // c0=0: forget term vanishes
        float hR = sigf(zo) * tanh_fast(cR);
        red[ca][ia] = fcW[36 + ia] * hR + fcW[ia] * h1s[ca][ia];
    }
    __syncthreads();
    if (tid < SG2) {
        float s2 = fcb[0];
        for (int j = 0; j < Hn; ++j) s2 += red[tid][j];
        out[base + tid] = s2;
    }
}

// ================= FALLBACK PATH (zero workspace, ckpt/recompute) ============
__global__ __launch_bounds__(G4, 1) void fused_all_kernel(
    const float* __restrict__ x,
    const float* __restrict__ Wih0f, const float* __restrict__ Whh0f,
    const float* __restrict__ bih0f, const float* __restrict__ bhh0f,
    const float* __restrict__ Wih0r, const float* __restrict__ Whh0r,
    const float* __restrict__ bih0r, const float* __restrict__ bhh0r,
    const float* __restrict__ Wih1f, const float* __restrict__ Whh1f,
    const float* __restrict__ bih1f, const float* __restrict__ bhh1f,
    const float* __restrict__ Wih1r,
    const float* __restrict__ bih1r, const float* __restrict__ bhh1r,
    const float* __restrict__ fcW, const float* __restrict__ fcb,
    float* __restrict__ out)
{
    const int g = threadIdx.x;
    const int b = blockIdx.x;

    __shared__ float xs[TT];
    __shared__ float cbuf[64][Hn];
    __shared__ float ckpt_h[8][Hn], ckpt_c[8][Hn];
    __shared__ float hr[40], h0s[80], hs1[40], zs[G4], red[40];

    for (int i = g; i < TT; i += G4) xs[i] = x[(size_t)b * TT + i];

    float wr[Hn], wf[Hn];
#pragma unroll
    for (int k = 0; k < Hn; ++k) wr[k] = Whh0r[g * Hn + k];
#pragma unroll
    for (int k = 0; k < Hn; ++k) wf[k] = Whh0f[g * Hn + k];
    const float wxr = Wih0r[g], br = bih0r[g] + bhh0r[g];
    const float wxf = Wih0f[g], bf = bih0f[g] + bhh0f[g];
    float w1i[72];
#pragma unroll
    for (int k = 0; k < 72; ++k) w1i[k] = Wih1f[g * 72 + k];
    float w1h[Hn];
#pragma unroll
    for (int k = 0; k < Hn; ++k) w1h[k] = Whh1f[g * Hn + k];
    const float b1 = bih1f[g] + bhh1f[g];

    if (g < Hn) hr[g] = 0.0f;
    float cr = 0.0f;
    __syncthreads();
    for (int s = 0; s < TT; ++s) {
        const int t = TT - 1 - s;
        if ((t & 63) == 63 && g < Hn) { ckpt_h[t >> 6][g] = hr[g]; ckpt_c[t >> 6][g] = cr; }
        float z0 = fmaf(xs[t], wxr, br), z1 = 0.f, z2 = 0.f, z3 = 0.f;
        DOT36(wr, hr, z0, z1, z2, z3);
        zs[g] = (z0 + z1) + (z2 + z3);
        __syncthreads();
        if (g < Hn) {
            float zi = zs[g], zf = zs[g + 36], zg = zs[g + 72], zo = zs[g + 108];
            cr = sigf(zf) * cr + sigf(zi) * tanh_fast(zg);
            hr[g] = sigf(zo) * tanh_fast(cr);
        }
        __syncthreads();
    }

    if (g < Hn) { h0s[g] = 0.0f; hs1[g] = 0.0f; }
    float c0 = 0.0f, c1 = 0.0f;
    __syncthreads();

    for (int m = 0; m < 8; ++m) {
        if (g < Hn) { hr[g] = ckpt_h[m][g]; cr = ckpt_c[m][g]; }
        __syncthreads();
        for (int j = 0; j < 64; ++j) {
            const int t = m * 64 + 63 - j;
            float z0 = fmaf(xs[t], wxr, br), z1 = 0.f, z2 = 0.f, z3 = 0.f;
            DOT36(wr, hr, z0, z1, z2, z3);
            zs[g] = (z0 + z1) + (z2 + z3);
            __syncthreads();
            if (g < Hn) {
                float zi = zs[g], zf = zs[g + 36], zg = zs[g + 72], zo = zs[g + 108];
                cr = sigf(zf) * cr + sigf(zi) * tanh_fast(zg);
                float h = sigf(zo) * tanh_fast(cr);
                hr[g] = h;
                cbuf[t & 63][g] = h;
            }
            __syncthreads();
        }
        for (int j = 0; j < 64; ++j) {
            const int t = m * 64 + j;
            float z0 = fmaf(xs[t], wxf, bf), z1 = 0.f, z2 = 0.f, z3 = 0.f;
            DOT36(wf, h0s, z0, z1, z2, z3);
            zs[g] = (z0 + z1) + (z2 + z3);
            __syncthreads();
            if (g < Hn) {
                float zi = zs[g], zf = zs[g + 36], zg = zs[g + 72], zo = zs[g + 108];
                c0 = sigf(zf) * c0 + sigf(zi) * tanh_fast(zg);
                h0s[g] = sigf(zo) * tanh_fast(c0);
            } else if (g < 72) {
                h0s[g] = cbuf[j][g - 36];
            }
            __syncthreads();
            float y0 = b1, y1 = 0.f, y2 = 0.f, y3 = 0.f;
            DOT72(w1i, h0s, y0, y1, y2, y3);
            DOT36(w1h, hs1, y0, y1, y2, y3);
            zs[g] = (y0 + y1) + (y2 + y3);
            __syncthreads();
            if (g < Hn) {
                float zi = zs[g], zf = zs[g + 36], zg = zs[g + 72], zo = zs[g + 108];
                c1 = sigf(zf) * c1 + sigf(zi) * tanh_fast(zg);
                hs1[g] = sigf(zo) * tanh_fast(c1);
            }
            __syncthreads();
        }
    }

    float zR = bih1r[g] + bhh1r[g];
#pragma unroll
    for (int k = 0; k < 72; ++k) zR = fmaf(Wih1r[g * 72 + k], h0s[k], zR);
    zs[g] = zR;
    __syncthreads();
    if (g < Hn) {
        float zi = zs[g], zg = zs[g + 72], zo = zs[g + 108];
        float c  = sigf(zi) * tanh_fast(zg);
        float hrv = sigf(zo) * tanh_fast(c);
        red[g] = fcW[36 + g] * hrv + fcW[g] * hs1[g];
    }
    __syncthreads();
    if (g == 0) {
        float s = fcb[0];
        for (int j = 0; j < Hn; ++j) s += red[j];
        out[b] = s;
    }
}

extern "C" void kernel_launch(void* const* d_in, const int* in_sizes, int n_in,
                              void* d_out, int out_size, void* d_ws, size_t ws_size,
                              hipStream_t stream)
{
    const float* x     = (const float*)d_in[0];
    const float* Wih0f = (const float*)d_in[1];
    const float* Whh0f = (const float*)d_in[2];
    const float* bih0f = (const float*)d_in[3];
    const float* bhh0f = (const float*)d_in[4];
    const float* Wih0r = (const float*)d_in[5];
    const float* Whh0r = (const float*)d_in[6];
    const float* bih0r = (const float*)d_in[7];
    const float* bhh0r = (const float*)d_in[8];
    const float* Wih1f = (const float*)d_in[9];
    const float* Whh1f = (const float*)d_in[10];
    const float* bih1f = (const float*)d_in[11];
    const float* bhh1f = (const float*)d_in[12];
    const float* Wih1r = (const float*)d_in[13];
    const float* bih1r = (const float*)d_in[15];
    const float* bhh1r = (const float*)d_in[16];
    const float* fcW   = (const float*)d_in[17];
    const float* fcb   = (const float*)d_in[18];

    const size_t need = (size_t)BB * TT * Hn * sizeof(float);   // 151 MB (known-safe)
    if (d_ws != nullptr && ws_size >= need) {
        float* h0r = (float*)d_ws;
        l0rev_kernel<<<BB / SG1, NTK1, 0, stream>>>(x, Wih0r, Whh0r, bih0r, bhh0r, h0r);
        fused_fl_kernel<<<NB2, NT2, 0, stream>>>(
            x, Wih0f, Whh0f, bih0f, bhh0f, Wih1f, Whh1f, bih1f, bhh1f,
            Wih1r, bih1r, bhh1r, fcW, fcb, h0r, (float*)d_out);
    } else {
        fused_all_kernel<<<BB, G4, 0, stream>>>(
            x, Wih0f, Whh0f, bih0f, bhh0f, Wih0r, Whh0r, bih0r, bhh0r,
            Wih1f, Whh1f, bih1f, bhh1f, Wih1r, bih1r, bhh1r, fcW, fcb,
            (float*)d_out);
    }
}

// Round 15
// 1876.787 us; speedup vs baseline: 3.1740x; 1.0683x over previous
//
#include <hip/hip_runtime.h>
#include <cstdint>

#define Hn 36
#define G4 144          // 4*H gate rows
#define TT 512
#define BB 2048

__device__ __forceinline__ float sigf(float x) { return 1.0f / (1.0f + __expf(-x)); }
__device__ __forceinline__ float tanh_fast(float x) {
    float e = __expf(2.0f * x);          // exact +-1 limits via over/underflow
    return 1.0f - 2.0f / (e + 1.0f);
}

// ---- K1 named-register weight quads (K1 verified ~420us; untouched) ----
#define REP9(M, P)  M(P,0) M(P,1) M(P,2) M(P,3) M(P,4) M(P,5) M(P,6) M(P,7) M(P,8)
#define DECLQ(P, i) float P##i##x, P##i##y, P##i##z, P##i##w;
#define LOADQ(P, i) { float4 _t = wp[i]; P##i##x = _t.x; P##i##y = _t.y; P##i##z = _t.z; P##i##w = _t.w; }
#define PINQ(P, i)  asm volatile("" : "+v"(P##i##x), "+v"(P##i##y), "+v"(P##i##z), "+v"(P##i##w));
#define FMAQ(P, i)                                                        \
    {  float4 hv = *(const float4*)&hb[(i) * 4];                          \
       z0 = fmaf(P##i##x, hv.x, z0); z1 = fmaf(P##i##y, hv.y, z1);        \
       z2 = fmaf(P##i##z, hv.z, z2); z3 = fmaf(P##i##w, hv.w, z3); }

// array-based dots (fallback kernel only)
#define DOT36(W, H, Z0, Z1, Z2, Z3)                        \
    do {                                                   \
        _Pragma("unroll") for (int _k = 0; _k < 9; ++_k) { \
            float4 hv = *(const float4*)&(H)[_k * 4];      \
            Z0 = fmaf((W)[_k * 4 + 0], hv.x, Z0);          \
            Z1 = fmaf((W)[_k * 4 + 1], hv.y, Z1);          \
            Z2 = fmaf((W)[_k * 4 + 2], hv.z, Z2);          \
            Z3 = fmaf((W)[_k * 4 + 3], hv.w, Z3);          \
        }                                                  \
    } while (0)

#define DOT72(W, H, Z0, Z1, Z2, Z3)                         \
    do {                                                    \
        _Pragma("unroll") for (int _k = 0; _k < 18; ++_k) { \
            float4 hv = *(const float4*)&(H)[_k * 4];       \
            Z0 = fmaf((W)[_k * 4 + 0], hv.x, Z0);           \
            Z1 = fmaf((W)[_k * 4 + 1], hv.y, Z1);           \
            Z2 = fmaf((W)[_k * 4 + 2], hv.z, Z2);           \
            Z3 = fmaf((W)[_k * 4 + 3], hv.w, Z3);           \
        }                                                   \
    } while (0)

// ============ K1: layer-0 REVERSE scan, full batch -> h0r (151 MB ws) ========
#define SG1 4
#define NTK1 (SG1 * G4)   // 576
__global__ __launch_bounds__(NTK1) void l0rev_kernel(
    const float* __restrict__ x,
    const float* __restrict__ Wih, const float* __restrict__ Whh,
    const float* __restrict__ bih, const float* __restrict__ bhh,
    float* __restrict__ h0r)
{
    const int tid = threadIdx.x;
    const int cc  = tid / G4;
    const int g   = tid % G4;
    const int b   = blockIdx.x * SG1 + cc;

    __shared__ float xs[SG1][TT];
    __shared__ float hs[SG1][40];
    __shared__ float zs[SG1][G4];

    for (int i = g; i < TT; i += G4) xs[cc][i] = x[(size_t)b * TT + i];

    REP9(DECLQ, R)
    {
        const float4* wp = (const float4*)(Whh + g * Hn);
        REP9(LOADQ, R)
    }
    float wx   = Wih[g];
    float bias = bih[g] + bhh[g];
    REP9(PINQ, R)
    asm volatile("" : "+v"(wx), "+v"(bias));

    if (g < 40) hs[cc][g] = 0.0f;
    float c = 0.0f;
    __syncthreads();

    float* dst = h0r + (size_t)b * TT * Hn;

    for (int s = 0; s < TT; ++s) {
        const int t = TT - 1 - s;
        float z0 = fmaf(xs[cc][t], wx, bias), z1 = 0.f, z2 = 0.f, z3 = 0.f;
        {
            const float* hb = hs[cc];
            REP9(FMAQ, R)
        }
        zs[cc][g] = (z0 + z1) + (z2 + z3);
        __syncthreads();
        if (g < Hn) {
            float zi = zs[cc][g], zf = zs[cc][g + 36], zg = zs[cc][g + 72], zo = zs[cc][g + 108];
            c = sigf(zf) * c + sigf(zi) * tanh_fast(zg);
            float h = sigf(zo) * tanh_fast(c);
            hs[cc][g] = h;
            dst[(size_t)t * Hn + g] = h;
        }
        __syncthreads();
    }
}

// ====== K2: skewed fusion, 8 chains/block, LDS weights, 2-row x 4-chain ======
// Dot groups: 0:Whh0f.h0f(+x)  1:Wih1f[:, :36].h0f  2:Wih1f[:, 36:].h0r  3:Whh1f.h1
// Thread = (sub: chain half, gp: group, rr: row pair {rr, rr+72}).
// Combine roles (verified r14): tid<288 -> L0 state; tid>=288 -> L1 state + h0r staging.
#define SG2  8
#define NT2  576
#define NB2  (BB / SG2)   // 256 blocks = 1/CU
#define W1ST 76           // Wih1f row stride in LDS

__global__ __launch_bounds__(NT2) void fused_fl_kernel(
    const float* __restrict__ x,
    const float* __restrict__ Wih0f, const float* __restrict__ Whh0f,
    const float* __restrict__ bih0f, const float* __restrict__ bhh0f,
    const float* __restrict__ Wih1f, const float* __restrict__ Whh1f,
    const float* __restrict__ bih1f, const float* __restrict__ bhh1f,
    const float* __restrict__ Wih1r,
    const float* __restrict__ bih1r, const float* __restrict__ bhh1r,
    const float* __restrict__ fcW, const float* __restrict__ fcb,
    const float* __restrict__ h0r,
    float* __restrict__ out)
{
    const int tid  = threadIdx.x;
    const int sub  = tid / 288;          // chain half (0: chains 0-3, 1: 4-7)
    const int idx  = tid % 288;
    const int gp   = idx / 72;           // dot group 0..3
    const int rr   = idx % 72;           // row pair: rows rr, rr+72
    const int ch0  = sub * 4;            // first chain of this thread's half
    const int base = blockIdx.x * SG2;
    // combine roles (identical to r14)
    const int ca = tid / Hn;             // L0 chain (tid<288)
    const int ia = tid % Hn;             // L0 unit
    const int ct = tid - 288;            // L1 role index
    const int cb = (ct >= 0) ? ct / Hn : 0;
    const int ib = (ct >= 0) ? ct % Hn : 0;

    __shared__ float wt0[G4 * 36];       // Whh0f
    __shared__ float wt1[G4 * W1ST];     // Wih1f (padded rows)
    __shared__ float wt3[G4 * 36];       // Whh1f
    __shared__ float xs[SG2][TT + 2];
    __shared__ float h0f[2][SG2][40];
    __shared__ float h0rs[2][SG2][40];
    __shared__ float h1s[SG2][40];
    __shared__ float zF[SG2][G4];
    __shared__ float zL[3][SG2][G4];
    __shared__ float red[SG2][Hn];

    // ---------------- one-time staging ----------------
    for (int i = tid; i < G4 * 36; i += NT2) wt0[i] = Whh0f[i];
    for (int i = tid; i < G4 * 72; i += NT2)
        wt1[(i / 72) * W1ST + (i % 72)] = Wih1f[i];
    for (int i = tid; i < G4 * 36; i += NT2) wt3[i] = Whh1f[i];
    for (int i = tid; i < SG2 * (TT + 2); i += NT2) {
        int c = i / (TT + 2), t = i % (TT + 2);
        xs[c][t] = (t < TT) ? x[(size_t)(base + c) * TT + t] : 0.0f;
    }
    for (int i = tid; i < 2 * SG2 * 40; i += NT2) {
        (&h0f[0][0][0])[i] = 0.0f;
        (&h0rs[0][0][0])[i] = 0.0f;
    }
    for (int i = tid; i < SG2 * 40; i += NT2) (&h1s[0][0])[i] = 0.0f;

    const int r0 = rr, r1 = rr + 72;
    const float* wr0;
    const float* wr1;
    if (gp == 0)      { wr0 = &wt0[r0 * 36];        wr1 = &wt0[r1 * 36]; }
    else if (gp == 1) { wr0 = &wt1[r0 * W1ST];      wr1 = &wt1[r1 * W1ST]; }
    else if (gp == 2) { wr0 = &wt1[r0 * W1ST + 36]; wr1 = &wt1[r1 * W1ST + 36]; }
    else              { wr0 = &wt3[r0 * 36];        wr1 = &wt3[r1 * 36]; }
    const float wxA = (gp == 0) ? Wih0f[r0] : 0.0f;
    const float wxB = (gp == 0) ? Wih0f[r1] : 0.0f;
    const float bsA = (gp == 0) ? (bih0f[r0] + bhh0f[r0])
                    : (gp == 3) ? (bih1f[r0] + bhh1f[r0]) : 0.0f;
    const float bsB = (gp == 0) ? (bih0f[r1] + bhh0f[r1])
                    : (gp == 3) ? (bih1f[r1] + bhh1f[r1]) : 0.0f;
    float* zt = (gp == 0) ? &zF[0][0] : &zL[gp - 1][0][0];

    const float* srow = h0r + (size_t)(base + cb) * TT * Hn + ib;   // L1-role h0r stream
    float cs0 = 0.0f, cs1 = 0.0f, rvv = 0.0f;
    __syncthreads();

    // ---- prologue: h0f(0) = step(h=0, x0); stage h0r(0); prefetch h0r(1) ----
    if (gp == 0) {
#pragma unroll
        for (int c = 0; c < 4; ++c) {
            zF[ch0 + c][r0] = fmaf(xs[ch0 + c][0], wxA, bsA);
            zF[ch0 + c][r1] = fmaf(xs[ch0 + c][0], wxB, bsB);
        }
    }
    if (ct >= 0) {
        h0rs[0][cb][ib] = srow[0];
        rvv = srow[Hn];
    }
    __syncthreads();
    if (tid < 288) {
        float zi = zF[ca][ia], zg = zF[ca][ia + 72], zo = zF[ca][ia + 108];
        cs0 = sigf(zi) * tanh_fast(zg);       // c=0 start: forget term vanishes
        h0f[0][ca][ia] = sigf(zo) * tanh_fast(cs0);
    }
    __syncthreads();

    int cur = 0;
    for (int t = 0; t < TT; ++t) {
        float rv2 = (ct >= 0 && t + 2 < TT) ? srow[(size_t)(t + 2) * Hn] : 0.0f;

        const float* hb = (gp <= 1) ? &h0f[cur][ch0][0]
                        : (gp == 2) ? &h0rs[cur][ch0][0] : &h1s[ch0][0];
        // branchless init: wxA/B = 0 and bsA/B in {0, b1} for non-gp0 groups
        float x0v = xs[ch0 + 0][t + 1], x1v = xs[ch0 + 1][t + 1];
        float x2v = xs[ch0 + 2][t + 1], x3v = xs[ch0 + 3][t + 1];
        float a00 = fmaf(x0v, wxA, bsA), a01 = fmaf(x1v, wxA, bsA);
        float a02 = fmaf(x2v, wxA, bsA), a03 = fmaf(x3v, wxA, bsA);
        float a10 = fmaf(x0v, wxB, bsB), a11 = fmaf(x1v, wxB, bsB);
        float a12 = fmaf(x2v, wxB, bsB), a13 = fmaf(x3v, wxB, bsB);

#pragma unroll
        for (int i = 0; i < 9; ++i) {
            float4 w0 = *(const float4*)&wr0[i * 4];
            float4 w1 = *(const float4*)&wr1[i * 4];
            float4 h;
            h = *(const float4*)&hb[0 * 40 + i * 4];
            a00 = fmaf(w0.x, h.x, a00); a00 = fmaf(w0.y, h.y, a00);
            a00 = fmaf(w0.z, h.z, a00); a00 = fmaf(w0.w, h.w, a00);
            a10 = fmaf(w1.x, h.x, a10); a10 = fmaf(w1.y, h.y, a10);
            a10 = fmaf(w1.z, h.z, a10); a10 = fmaf(w1.w, h.w, a10);
            h = *(const float4*)&hb[1 * 40 + i * 4];
            a01 = fmaf(w0.x, h.x, a01); a01 = fmaf(w0.y, h.y, a01);
            a01 = fmaf(w0.z, h.z, a01); a01 = fmaf(w0.w, h.w, a01);
            a11 = fmaf(w1.x, h.x, a11); a11 = fmaf(w1.y, h.y, a11);
            a11 = fmaf(w1.z, h.z, a11); a11 = fmaf(w1.w, h.w, a11);
            h = *(const float4*)&hb[2 * 40 + i * 4];
            a02 = fmaf(w0.x, h.x, a02); a02 = fmaf(w0.y, h.y, a02);
            a02 = fmaf(w0.z, h.z, a02); a02 = fmaf(w0.w, h.w, a02);
            a12 = fmaf(w1.x, h.x, a12); a12 = fmaf(w1.y, h.y, a12);
            a12 = fmaf(w1.z, h.z, a12); a12 = fmaf(w1.w, h.w, a12);
            h = *(const float4*)&hb[3 * 40 + i * 4];
            a03 = fmaf(w0.x, h.x, a03); a03 = fmaf(w0.y, h.y, a03);
            a03 = fmaf(w0.z, h.z, a03); a03 = fmaf(w0.w, h.w, a03);
            a13 = fmaf(w1.x, h.x, a13); a13 = fmaf(w1.y, h.y, a13);
            a13 = fmaf(w1.z, h.z, a13); a13 = fmaf(w1.w, h.w, a13);
        }
        zt[(ch0 + 0) * G4 + r0] = a00; zt[(ch0 + 1) * G4 + r0] = a01;
        zt[(ch0 + 2) * G4 + r0] = a02; zt[(ch0 + 3) * G4 + r0] = a03;
        zt[(ch0 + 0) * G4 + r1] = a10; zt[(ch0 + 1) * G4 + r1] = a11;
        zt[(ch0 + 2) * G4 + r1] = a12; zt[(ch0 + 3) * G4 + r1] = a13;
        __syncthreads();

        if (tid < 288) {                       // L0 combine -> h0f(t+1)
            if (t + 1 < TT) {
                float zi = zF[ca][ia],       zf = zF[ca][ia + 36];
                float zg = zF[ca][ia + 72],  zo = zF[ca][ia + 108];
                cs0 = sigf(zf) * cs0 + sigf(zi) * tanh_fast(zg);
                h0f[cur ^ 1][ca][ia] = sigf(zo) * tanh_fast(cs0);
            }
        } else {                               // L1 combine -> h1(t); stage h0r(t+1)
            float zi = zL[0][cb][ib]       + zL[1][cb][ib]       + zL[2][cb][ib];
            float zf = zL[0][cb][ib + 36]  + zL[1][cb][ib + 36]  + zL[2][cb][ib + 36];
            float zg = zL[0][cb][ib + 72]  + zL[1][cb][ib + 72]  + zL[2][cb][ib + 72];
            float zo = zL[0][cb][ib + 108] + zL[1][cb][ib + 108] + zL[2][cb][ib + 108];
            cs1 = sigf(zf) * cs1 + sigf(zi) * tanh_fast(zg);
            h1s[cb][ib] = sigf(zo) * tanh_fast(cs1);
            if (t + 1 < TT) h0rs[cur ^ 1][cb][ib] = rvv;
        }
        __syncthreads();
        rvv = rv2;
        if (t + 1 < TT) cur ^= 1;
    }

    // ---- tail: L1 reverse single step at t=T-1 (h0=c0=0) + FC ----
    {
        const int gpT = tid / G4, gT = tid % G4;
#pragma unroll
        for (int sub2 = 0; sub2 < 2; ++sub2) {
            const int cc = gpT * 2 + sub2;
            float zR = bih1r[gT] + bhh1r[gT];
            const float* wrq = Wih1r + gT * 72;
#pragma unroll
            for (int k = 0; k < Hn; ++k) zR = fmaf(wrq[k],      h0f[cur][cc][k],  zR);
#pragma unroll
            for (int k = 0; k < Hn; ++k) zR = fmaf(wrq[36 + k], h0rs[cur][cc][k], zR);
            zF[cc][gT] = zR;
        }
    }
    __syncthreads();
    if (tid < 288) {
        float zi = zF[ca][ia], zg = zF[ca][ia + 72], zo = zF[ca][ia + 108];
        float cR = sigf(zi) * tanh_fast(zg);   // c0=0: forget term vanishes
        float hR = sigf(zo) * tanh_fast(cR);
        red[ca][ia] = fcW[36 + ia] * hR + fcW[ia] * h1s[ca][ia];
    }
    __syncthreads();
    if (tid < SG2) {
        float s2 = fcb[0];
        for (int j = 0; j < Hn; ++j) s2 += red[tid][j];
        out[base + tid] = s2;
    }
}

// ================= FALLBACK PATH (zero workspace, ckpt/recompute) ============
__global__ __launch_bounds__(G4, 1) void fused_all_kernel(
    const float* __restrict__ x,
    const float* __restrict__ Wih0f, const float* __restrict__ Whh0f,
    const float* __restrict__ bih0f, const float* __restrict__ bhh0f,
    const float* __restrict__ Wih0r, const float* __restrict__ Whh0r,
    const float* __restrict__ bih0r, const float* __restrict__ bhh0r,
    const float* __restrict__ Wih1f, const float* __restrict__ Whh1f,
    const float* __restrict__ bih1f, const float* __restrict__ bhh1f,
    const float* __restrict__ Wih1r,
    const float* __restrict__ bih1r, const float* __restrict__ bhh1r,
    const float* __restrict__ fcW, const float* __restrict__ fcb,
    float* __restrict__ out)
{
    const int g = threadIdx.x;
    const int b = blockIdx.x;

    __shared__ float xs[TT];
    __shared__ float cbuf[64][Hn];
    __shared__ float ckpt_h[8][Hn], ckpt_c[8][Hn];
    __shared__ float hr[40], h0s[80], hs1[40], zs[G4], red[40];

    for (int i = g; i < TT; i += G4) xs[i] = x[(size_t)b * TT + i];

    float wr[Hn], wf[Hn];
#pragma unroll
    for (int k = 0; k < Hn; ++k) wr[k] = Whh0r[g * Hn + k];
#pragma unroll
    for (int k = 0; k < Hn; ++k) wf[k] = Whh0f[g * Hn + k];
    const float wxr = Wih0r[g], br = bih0r[g] + bhh0r[g];
    const float wxf = Wih0f[g], bf = bih0f[g] + bhh0f[g];
    float w1i[72];
#pragma unroll
    for (int k = 0; k < 72; ++k) w1i[k] = Wih1f[g * 72 + k];
    float w1h[Hn];
#pragma unroll
    for (int k = 0; k < Hn; ++k) w1h[k] = Whh1f[g * Hn + k];
    const float b1 = bih1f[g] + bhh1f[g];

    if (g < Hn) hr[g] = 0.0f;
    float cr = 0.0f;
    __syncthreads();
    for (int s = 0; s < TT; ++s) {
        const int t = TT - 1 - s;
        if ((t & 63) == 63 && g < Hn) { ckpt_h[t >> 6][g] = hr[g]; ckpt_c[t >> 6][g] = cr; }
        float z0 = fmaf(xs[t], wxr, br), z1 = 0.f, z2 = 0.f, z3 = 0.f;
        DOT36(wr, hr, z0, z1, z2, z3);
        zs[g] = (z0 + z1) + (z2 + z3);
        __syncthreads();
        if (g < Hn) {
            float zi = zs[g], zf = zs[g + 36], zg = zs[g + 72], zo = zs[g + 108];
            cr = sigf(zf) * cr + sigf(zi) * tanh_fast(zg);
            hr[g] = sigf(zo) * tanh_fast(cr);
        }
        __syncthreads();
    }

    if (g < Hn) { h0s[g] = 0.0f; hs1[g] = 0.0f; }
    float c0 = 0.0f, c1 = 0.0f;
    __syncthreads();

    for (int m = 0; m < 8; ++m) {
        if (g < Hn) { hr[g] = ckpt_h[m][g]; cr = ckpt_c[m][g]; }
        __syncthreads();
        for (int j = 0; j < 64; ++j) {
            const int t = m * 64 + 63 - j;
            float z0 = fmaf(xs[t], wxr, br), z1 = 0.f, z2 = 0.f, z3 = 0.f;
            DOT36(wr, hr, z0, z1, z2, z3);
            zs[g] = (z0 + z1) + (z2 + z3);
            __syncthreads();
            if (g < Hn) {
                float zi = zs[g], zf = zs[g + 36], zg = zs[g + 72], zo = zs[g + 108];
                cr = sigf(zf) * cr + sigf(zi) * tanh_fast(zg);
                float h = sigf(zo) * tanh_fast(cr);
                hr[g] = h;
                cbuf[t & 63][g] = h;
            }
            __syncthreads();
        }
        for (int j = 0; j < 64; ++j) {
            const int t = m * 64 + j;
            float z0 = fmaf(xs[t], wxf, bf), z1 = 0.f, z2 = 0.f, z3 = 0.f;
            DOT36(wf, h0s, z0, z1, z2, z3);
            zs[g] = (z0 + z1) + (z2 + z3);
            __syncthreads();
            if (g < Hn) {
                float zi = zs[g], zf = zs[g + 36], zg = zs[g + 72], zo = zs[g + 108];
                c0 = sigf(zf) * c0 + sigf(zi) * tanh_fast(zg);
                h0s[g] = sigf(zo) * tanh_fast(c0);
            } else if (g < 72) {
                h0s[g] = cbuf[j][g - 36];
            }
            __syncthreads();
            float y0 = b1, y1 = 0.f, y2 = 0.f, y3 = 0.f;
            DOT72(w1i, h0s, y0, y1, y2, y3);
            DOT36(w1h, hs1, y0, y1, y2, y3);
            zs[g] = (y0 + y1) + (y2 + y3);
            __syncthreads();
            if (g < Hn) {
                float zi = zs[g], zf = zs[g + 36], zg = zs[g + 72], zo = zs[g + 108];
                c1 = sigf(zf) * c1 + sigf(zi) * tanh_fast(zg);
                hs1[g] = sigf(zo) * tanh_fast(c1);
            }
            __syncthreads();
        }
    }

    float zR = bih1r[g] + bhh1r[g];
#pragma unroll
    for (int k = 0; k < 72; ++k) zR = fmaf(Wih1r[g * 72 + k], h0s[k], zR);
    zs[g] = zR;
    __syncthreads();
    if (g < Hn) {
        float zi = zs[g], zg = zs[g + 72], zo = zs[g + 108];
        float c  = sigf(zi) * tanh_fast(zg);
        float hrv = sigf(zo) * tanh_fast(c);
        red[g] = fcW[36 + g] * hrv + fcW[g] * hs1[g];
    }
    __syncthreads();
    if (g == 0) {
        float s = fcb[0];
        for (int j = 0; j < Hn; ++j) s += red[j];
        out[b] = s;
    }
}

extern "C" void kernel_launch(void* const* d_in, const int* in_sizes, int n_in,
                              void* d_out, int out_size, void* d_ws, size_t ws_size,
                              hipStream_t stream)
{
    const float* x     = (const float*)d_in[0];
    const float* Wih0f = (const float*)d_in[1];
    const float* Whh0f = (const float*)d_in[2];
    const float* bih0f = (const float*)d_in[3];
    const float* bhh0f = (const float*)d_in[4];
    const float* Wih0r = (const float*)d_in[5];
    const float* Whh0r = (const float*)d_in[6];
    const float* bih0r = (const float*)d_in[7];
    const float* bhh0r = (const float*)d_in[8];
    const float* Wih1f = (const float*)d_in[9];
    const float* Whh1f = (const float*)d_in[10];
    const float* bih1f = (const float*)d_in[11];
    const float* bhh1f = (const float*)d_in[12];
    const float* Wih1r = (const float*)d_in[13];
    const float* bih1r = (const float*)d_in[15];
    const float* bhh1r = (const float*)d_in[16];
    const float* fcW   = (const float*)d_in[17];
    const float* fcb   = (const float*)d_in[18];

    const size_t need = (size_t)BB * TT * Hn * sizeof(float);   // 151 MB (known-safe)
    if (d_ws != nullptr && ws_size >= need) {
        float* h0r = (float*)d_ws;
        l0rev_kernel<<<BB / SG1, NTK1, 0, stream>>>(x, Wih0r, Whh0r, bih0r, bhh0r, h0r);
        fused_fl_kernel<<<NB2, NT2, 0, stream>>>(
            x, Wih0f, Whh0f, bih0f, bhh0f, Wih1f, Whh1f, bih1f, bhh1f,
            Wih1r, bih1r, bhh1r, fcW, fcb, h0r, (float*)d_out);
    } else {
        fused_all_kernel<<<BB, G4, 0, stream>>>(
            x, Wih0f, Whh0f, bih0f, bhh0f, Wih0r, Whh0r, bih0r, bhh0r,
            Wih1f, Whh1f, bih1f, bhh1f, Wih1r, bih1r, bhh1r, fcW, fcb,
            (float*)d_out);
    }
}